// Round 2
// baseline (154.093 us; speedup 1.0000x reference)
//
#include <hip/hip_runtime.h>
#include <hip/hip_bf16.h>

#define D_DIM 1024
#define S_DIM 2048
#define B_DIM 4
#define KTAPS 16

typedef short bf16x8 __attribute__((ext_vector_type(8)));
typedef float f32x4 __attribute__((ext_vector_type(4)));
typedef short s16x8 __attribute__((ext_vector_type(8)));

// async global->LDS, 16B per lane (global_load_lds_dwordx4)
#define GLOAD16(gptr, lptr) \
  __builtin_amdgcn_global_load_lds((const __attribute__((address_space(1))) unsigned int*)(gptr), \
                                   (__attribute__((address_space(3))) unsigned int*)(lptr), 16, 0, 0)

static __device__ __forceinline__ short f2bs(float f) {
  __hip_bfloat16 h = __float2bfloat16(f);
  return *reinterpret_cast<short*>(&h);
}

// ---------------------------------------------------------------------------
// Kernel 1: taps only. 64 blocks; impulse response g_k[d] = C_d.A_d^k.B_d
// (Dm folded into tap 0).
// ---------------------------------------------------------------------------
__global__ void taps_kernel(const float* __restrict__ A, const float* __restrict__ Bm,
                            const float* __restrict__ Cm, const float* __restrict__ Dm,
                            float* __restrict__ gT) {
  const int gb   = blockIdx.x;         // 0..63
  const int wid  = threadIdx.x >> 6;   // 0..3
  const int lane = threadIdx.x & 63;
  const int sub  = lane >> 4;          // 0..3 (channel within wave)
  const int n    = lane & 15;          // state index
  const int d    = gb * 16 + wid * 4 + sub;
  float Ar[16];
#pragma unroll
  for (int m = 0; m < 16; ++m) Ar[m] = A[d * 256 + n * 16 + m];
  float v = Bm[d * 16 + n];
  const float c   = Cm[d * 16 + n];
  const float dmv = Dm[d];
  const int base  = sub << 4;
  for (int k = 0; k < KTAPS; ++k) {
    float dot = c * v;
    dot += __shfl_xor(dot, 1);
    dot += __shfl_xor(dot, 2);
    dot += __shfl_xor(dot, 4);
    dot += __shfl_xor(dot, 8);
    if (k == 0) dot += dmv;            // fold the D x_t skip term into tap 0
    if (n == 0) gT[k * D_DIM + d] = dot;
    float nv = 0.f;
#pragma unroll
    for (int m = 0; m < 16; ++m) nv = fmaf(Ar[m], __shfl(v, base + m), nv);
    v = nv;
  }
}

// ---------------------------------------------------------------------------
// Kernel 2 (fused): conv(16 taps) + LayerNorm + exact GELU -> Act (bf16,
// row-major). Blocks [0,2048): 4 consecutive rows, 256 threads, thread owns
// 4 d-cols; x window (19 rows x float4) in registers, g streamed k-outer.
// Blocks [2048,2560): vectorized W_out -> bf16 cast (8 elems/thread).
// ---------------------------------------------------------------------------
__global__ __launch_bounds__(256) void convln_kernel(const float* __restrict__ x,
                                                     const float* __restrict__ gT,
                                                     const float* __restrict__ lnw,
                                                     const float* __restrict__ lnb,
                                                     const float* __restrict__ W,
                                                     __hip_bfloat16* __restrict__ Wb,
                                                     __hip_bfloat16* __restrict__ act) {
  if (blockIdx.x >= 2048) {
    // ---- W cast: 512 blocks * 256 threads * 8 elems = 1024*1024 ----
    const int base = ((blockIdx.x - 2048) * 256 + threadIdx.x) * 8;
    const f32x4 w0 = *(const f32x4*)(W + base);
    const f32x4 w1 = *(const f32x4*)(W + base + 4);
    s16x8 o;
#pragma unroll
    for (int c = 0; c < 4; ++c) { o[c] = f2bs(w0[c]); o[4 + c] = f2bs(w1[c]); }
    *(s16x8*)((short*)Wb + base) = o;
    return;
  }

  __shared__ float redS[16];   // [j*4 + wid]
  __shared__ float redQ[16];
  const int m0  = blockIdx.x * 4;      // global row (0..8191)
  const int b   = m0 >> 11;            // batch
  const int s0  = m0 & 2047;           // seq pos of row j=0
  const int tid = threadIdx.x;
  const int lane = tid & 63, wid = tid >> 6;
  const int d0  = tid * 4;
  const float* xb = x + ((size_t)b * S_DIM) * D_DIM + d0;

  // x window: w[i] = x[s0-15+i], i=0..18 (zero for s<0)
  f32x4 w[19];
#pragma unroll
  for (int i = 0; i < 19; ++i) {
    const int s = s0 - 15 + i;
    w[i] = (s >= 0) ? *(const f32x4*)(xb + (size_t)s * D_DIM) : (f32x4){0.f, 0.f, 0.f, 0.f};
  }

  // conv: 4 rows, k-outer (one g float4 live at a time)
  f32x4 a[4] = {(f32x4){0,0,0,0}, (f32x4){0,0,0,0}, (f32x4){0,0,0,0}, (f32x4){0,0,0,0}};
#pragma unroll
  for (int k = 0; k < KTAPS; ++k) {
    const f32x4 g4 = *(const f32x4*)(gT + k * D_DIM + d0);
#pragma unroll
    for (int j = 0; j < 4; ++j) {
      const f32x4 xv = w[15 + j - k];
#pragma unroll
      for (int c = 0; c < 4; ++c) a[j][c] = fmaf(g4[c], xv[c], a[j][c]);
    }
  }

  // LN partial sums for all 4 rows -> one barrier
#pragma unroll
  for (int j = 0; j < 4; ++j) {
    float s = a[j][0] + a[j][1] + a[j][2] + a[j][3];
    float q = a[j][0]*a[j][0] + a[j][1]*a[j][1] + a[j][2]*a[j][2] + a[j][3]*a[j][3];
    s += __shfl_xor(s, 1);  s += __shfl_xor(s, 2);  s += __shfl_xor(s, 4);
    s += __shfl_xor(s, 8);  s += __shfl_xor(s, 16); s += __shfl_xor(s, 32);
    q += __shfl_xor(q, 1);  q += __shfl_xor(q, 2);  q += __shfl_xor(q, 4);
    q += __shfl_xor(q, 8);  q += __shfl_xor(q, 16); q += __shfl_xor(q, 32);
    if (lane == 0) { redS[j * 4 + wid] = s; redQ[j * 4 + wid] = q; }
  }
  __syncthreads();

  const f32x4 w4 = *(const f32x4*)&lnw[d0];
  const f32x4 b4 = *(const f32x4*)&lnb[d0];
#pragma unroll
  for (int j = 0; j < 4; ++j) {
    const float sum = redS[j*4+0] + redS[j*4+1] + redS[j*4+2] + redS[j*4+3];
    const float sq  = redQ[j*4+0] + redQ[j*4+1] + redQ[j*4+2] + redQ[j*4+3];
    const float mu  = sum * (1.0f / D_DIM);
    const float var = sq * (1.0f / D_DIM) - mu * mu;
    const float inv = rsqrtf(var + 1e-5f);
    short4 o;
    short* op = &o.x;
#pragma unroll
    for (int c = 0; c < 4; ++c) {
      float t = (a[j][c] - mu) * inv * w4[c] + b4[c];
      float ge = 0.5f * t * (1.f + erff(t * 0.70710678118654752f));  // exact gelu
      op[c] = f2bs(ge);
    }
    *(short4*)((short*)act + (size_t)(m0 + j) * D_DIM + d0) = o;
  }
}

// ---------------------------------------------------------------------------
// Kernel 3: out = x + Act @ W^T + b_out.
// RESTRUCTURED: 128(M) x 64(N) tile, BK=64 -> grid 64x16 = 1024 blocks,
// LDS 24 KB, ~<=128 VGPR, __launch_bounds__(256,4) => 4 blocks/CU resident
// (vs 2 before). Cross-block TLP hides the per-k0 vmcnt(0)+barrier drain and
// the epilogue x-read/out-write bursts (m132 vs m97: BK=128/64KB LDS cost
// ~1.8x on this structure). Same verified XOR-swizzled LDS layout, now with
// 8 16B-chunks per 64-short row: chunk c of row r at slot (c ^ (r&7)).
// 4 waves (2M x 2N), wave = 64x32 via 4x2 MFMA 16x16x32.
// A-frag: lane holds Act[m = l16][kq*8 + kk + j]
// B-frag: lane holds W  [n = l16][kq*8 + kk + j]   (W row = out col)
// C/D   : col = lane&15, row = (lane>>4)*4 + reg
// ---------------------------------------------------------------------------
__global__ __launch_bounds__(256, 4) void gemm_kernel(const __hip_bfloat16* __restrict__ Act,
                                                      const __hip_bfloat16* __restrict__ Wb,
                                                      const float* __restrict__ x,
                                                      const float* __restrict__ bout,
                                                      float* __restrict__ out) {
  __shared__ short Al[128 * 64];  // 16 KB
  __shared__ short Bl[64 * 64];   //  8 KB
  const int tid  = threadIdx.x;
  const int lane = tid & 63;
  const int wave = tid >> 6;
  const int mBase = blockIdx.x * 128;   // 64 m-tiles
  const int nBase = blockIdx.y * 64;    // 16 n-tiles
  const int wm = (wave & 1) * 64;
  const int wn = (wave >> 1) * 32;
  const int l16 = lane & 15;
  const int kq  = lane >> 4;            // 0..3 k-quad

  // staging: row = 64 shorts = 8 x 16B chunks. thread t -> row (t>>3)
  // (+32/round), LDS slot (t&7) => fetch global chunk (t&7)^(row&7).
  // row&7 invariant across rounds (32 % 8 == 0).
  const int st = tid >> 3;                     // 0..31
  const int cg = (tid & 7) ^ (st & 7);         // global 16B chunk fetched
  const short* Ag = (const short*)Act + (size_t)(mBase + st) * D_DIM + cg * 8;
  const short* Bg = (const short*)Wb  + (size_t)(nBase + st) * D_DIM + cg * 8;
  short* Als = Al + tid * 8;   // round adds 2048 shorts (32 rows)
  short* Bls = Bl + tid * 8;

  f32x4 acc[4][2];
#pragma unroll
  for (int mt = 0; mt < 4; ++mt)
#pragma unroll
    for (int nt = 0; nt < 2; ++nt) acc[mt][nt] = (f32x4){0.f, 0.f, 0.f, 0.f};

  for (int k0 = 0; k0 < D_DIM; k0 += 64) {
    __syncthreads();                       // readers of previous tile done
#pragma unroll
    for (int r = 0; r < 4; ++r)            // A: 128 rows = 4 rounds of 32
      GLOAD16(Ag + (size_t)r * 32 * D_DIM + k0, Als + r * 2048);
#pragma unroll
    for (int r = 0; r < 2; ++r)            // B: 64 rows = 2 rounds of 32
      GLOAD16(Bg + (size_t)r * 32 * D_DIM + k0, Bls + r * 2048);
    __syncthreads();                       // staged data visible

#pragma unroll
    for (int kk = 0; kk < 64; kk += 32) {
      bf16x8 af[4], bfr[2];
      const int cgr = (kk >> 3) + kq;      // {kq, 4+kq}
#pragma unroll
      for (int mt = 0; mt < 4; ++mt) {
        const int r = wm + mt * 16 + l16;
        af[mt] = *(const bf16x8*)&Al[r * 64 + ((cgr ^ (r & 7)) << 3)];
      }
#pragma unroll
      for (int nt = 0; nt < 2; ++nt) {
        const int r = wn + nt * 16 + l16;
        bfr[nt] = *(const bf16x8*)&Bl[r * 64 + ((cgr ^ (r & 7)) << 3)];
      }
#pragma unroll
      for (int mt = 0; mt < 4; ++mt)
#pragma unroll
        for (int nt = 0; nt < 2; ++nt)
          acc[mt][nt] = __builtin_amdgcn_mfma_f32_16x16x32_bf16(af[mt], bfr[nt], acc[mt][nt], 0, 0, 0);
    }
  }

  const int r0 = kq * 4;
#pragma unroll
  for (int mt = 0; mt < 4; ++mt) {
    const int row = mBase + wm + mt * 16 + r0;
#pragma unroll
    for (int nt = 0; nt < 2; ++nt) {
      const int col = nBase + wn + nt * 16 + l16;
      const float bo = bout[col];
#pragma unroll
      for (int r = 0; r < 4; ++r) {
        const size_t idx = (size_t)(row + r) * D_DIM + col;
        __builtin_nontemporal_store(x[idx] + acc[mt][nt][r] + bo, &out[idx]);
      }
    }
  }
}

// ---------------------------------------------------------------------------
extern "C" void kernel_launch(void* const* d_in, const int* in_sizes, int n_in,
                              void* d_out, int out_size, void* d_ws, size_t ws_size,
                              hipStream_t stream) {
  const float* x    = (const float*)d_in[0];
  const float* A    = (const float*)d_in[1];
  const float* Bm   = (const float*)d_in[2];
  const float* Cm   = (const float*)d_in[3];
  const float* Dm   = (const float*)d_in[4];
  const float* lnw  = (const float*)d_in[5];
  const float* lnb  = (const float*)d_in[6];
  const float* Wout = (const float*)d_in[7];
  const float* bout = (const float*)d_in[8];
  float* out = (float*)d_out;

  char* ws = (char*)d_ws;
  float* gT            = (float*)ws;                        // 16*1024*4   = 64 KB
  __hip_bfloat16* Wb   = (__hip_bfloat16*)(ws + 262144);    // 1024*1024*2 = 2 MB, row-major
  __hip_bfloat16* Act  = (__hip_bfloat16*)(ws + 2359296);   // 8192*1024*2 = 16.75 MB, row-major

  taps_kernel<<<64, 256, 0, stream>>>(A, Bm, Cm, Dm, gT);
  convln_kernel<<<2560, 256, 0, stream>>>(x, gT, lnw, lnb, Wout, Wb, Act);
  gemm_kernel<<<dim3(64, 16), 256, 0, stream>>>(Act, Wb, x, bout, out);
}

// Round 3
// 148.575 us; speedup vs baseline: 1.0371x; 1.0371x over previous
//
#include <hip/hip_runtime.h>
#include <hip/hip_bf16.h>

#define D_DIM 1024
#define S_DIM 2048
#define B_DIM 4
#define KTAPS 16

typedef short bf16x8 __attribute__((ext_vector_type(8)));
typedef float f32x4 __attribute__((ext_vector_type(4)));
typedef short s16x8 __attribute__((ext_vector_type(8)));

// async global->LDS, 16B per lane (global_load_lds_dwordx4)
#define GLOAD16(gptr, lptr) \
  __builtin_amdgcn_global_load_lds((const __attribute__((address_space(1))) unsigned int*)(gptr), \
                                   (__attribute__((address_space(3))) unsigned int*)(lptr), 16, 0, 0)

static __device__ __forceinline__ short f2bs(float f) {
  __hip_bfloat16 h = __float2bfloat16(f);
  return *reinterpret_cast<short*>(&h);
}

// ---------------------------------------------------------------------------
// Kernel 1: taps. 64 blocks; impulse response g_k[d] = C_d.A_d^k.B_d
// (Dm folded into tap 0).
// ---------------------------------------------------------------------------
__global__ void taps_kernel(const float* __restrict__ A, const float* __restrict__ Bm,
                            const float* __restrict__ Cm, const float* __restrict__ Dm,
                            float* __restrict__ gT) {
  const int gb   = blockIdx.x;         // 0..63
  const int wid  = threadIdx.x >> 6;   // 0..3
  const int lane = threadIdx.x & 63;
  const int sub  = lane >> 4;          // 0..3 (channel within wave)
  const int n    = lane & 15;          // state index
  const int d    = gb * 16 + wid * 4 + sub;
  float Ar[16];
#pragma unroll
  for (int m = 0; m < 16; ++m) Ar[m] = A[d * 256 + n * 16 + m];
  float v = Bm[d * 16 + n];
  const float c   = Cm[d * 16 + n];
  const float dmv = Dm[d];
  const int base  = sub << 4;
  for (int k = 0; k < KTAPS; ++k) {
    float dot = c * v;
    dot += __shfl_xor(dot, 1);
    dot += __shfl_xor(dot, 2);
    dot += __shfl_xor(dot, 4);
    dot += __shfl_xor(dot, 8);
    if (k == 0) dot += dmv;            // fold the D x_t skip term into tap 0
    if (n == 0) gT[k * D_DIM + d] = dot;
    float nv = 0.f;
#pragma unroll
    for (int m = 0; m < 16; ++m) nv = fmaf(Ar[m], __shfl(v, base + m), nv);
    v = nv;
  }
}

// ---------------------------------------------------------------------------
// Kernel 2 (fused): conv(16 taps) + LayerNorm + exact GELU -> Act (bf16).
// RESTRUCTURED vs 50us version: 8 rows/block (was 4) and
// __launch_bounds__(256,2) so the allocator may use up to 256 VGPR.
// The 4-row version was allocated only 80 VGPR (compiler occupancy
// heuristic) -- not enough to hold the 19-entry f32x4 window + accs, so the
// conv phase serialized on rematerialized loads (50us, 25% HBM, VALU 29%).
// 8 rows/block: window = 23 f32x4 (92 VGPR) + 8 acc (32 VGPR) fits in ~180;
// halo read amplification drops 4.75x -> 2.9x (156->94 MB requests).
// Blocks [1024,1536): vectorized W_out -> bf16 cast (8 elems/thread).
// ---------------------------------------------------------------------------
__global__ __launch_bounds__(256, 2) void convln_kernel(const float* __restrict__ x,
                                                        const float* __restrict__ gT,
                                                        const float* __restrict__ lnw,
                                                        const float* __restrict__ lnb,
                                                        const float* __restrict__ W,
                                                        __hip_bfloat16* __restrict__ Wb,
                                                        __hip_bfloat16* __restrict__ act) {
  if (blockIdx.x >= 1024) {
    // ---- W cast: 512 blocks * 256 threads * 8 elems = 1024*1024 ----
    const int base = ((blockIdx.x - 1024) * 256 + threadIdx.x) * 8;
    const f32x4 w0 = *(const f32x4*)(W + base);
    const f32x4 w1 = *(const f32x4*)(W + base + 4);
    s16x8 o;
#pragma unroll
    for (int c = 0; c < 4; ++c) { o[c] = f2bs(w0[c]); o[4 + c] = f2bs(w1[c]); }
    *(s16x8*)((short*)Wb + base) = o;
    return;
  }

  __shared__ float redS[32];   // [j*4 + wid], j=0..7
  __shared__ float redQ[32];
  const int m0  = blockIdx.x * 8;      // global row (0..8191); 2048%8==0 so
  const int b   = m0 >> 11;            // blocks never straddle a batch
  const int s0  = m0 & 2047;           // seq pos of row j=0
  const int tid = threadIdx.x;
  const int lane = tid & 63, wid = tid >> 6;
  const int d0  = tid * 4;
  const float* xb = x + ((size_t)b * S_DIM) * D_DIM + d0;

  // x window: w[i] = x[s0-15+i], i=0..22 (zero for s<0); all 23 loads
  // independent -> full MLP, kept live in registers.
  f32x4 w[23];
#pragma unroll
  for (int i = 0; i < 23; ++i) {
    const int s = s0 - 15 + i;
    w[i] = (s >= 0) ? *(const f32x4*)(xb + (size_t)s * D_DIM) : (f32x4){0.f, 0.f, 0.f, 0.f};
  }

  // conv: 8 rows, k-outer (g float4 streamed)
  f32x4 a[8];
#pragma unroll
  for (int j = 0; j < 8; ++j) a[j] = (f32x4){0.f, 0.f, 0.f, 0.f};
#pragma unroll
  for (int k = 0; k < KTAPS; ++k) {
    const f32x4 g4 = *(const f32x4*)(gT + k * D_DIM + d0);
#pragma unroll
    for (int j = 0; j < 8; ++j) {
      const f32x4 xv = w[15 + j - k];
#pragma unroll
      for (int c = 0; c < 4; ++c) a[j][c] = fmaf(g4[c], xv[c], a[j][c]);
    }
  }

  // LN partial sums for all 8 rows -> one barrier
#pragma unroll
  for (int j = 0; j < 8; ++j) {
    float s = a[j][0] + a[j][1] + a[j][2] + a[j][3];
    float q = a[j][0]*a[j][0] + a[j][1]*a[j][1] + a[j][2]*a[j][2] + a[j][3]*a[j][3];
    s += __shfl_xor(s, 1);  s += __shfl_xor(s, 2);  s += __shfl_xor(s, 4);
    s += __shfl_xor(s, 8);  s += __shfl_xor(s, 16); s += __shfl_xor(s, 32);
    q += __shfl_xor(q, 1);  q += __shfl_xor(q, 2);  q += __shfl_xor(q, 4);
    q += __shfl_xor(q, 8);  q += __shfl_xor(q, 16); q += __shfl_xor(q, 32);
    if (lane == 0) { redS[j * 4 + wid] = s; redQ[j * 4 + wid] = q; }
  }
  __syncthreads();

  const f32x4 w4 = *(const f32x4*)&lnw[d0];
  const f32x4 b4 = *(const f32x4*)&lnb[d0];
#pragma unroll
  for (int j = 0; j < 8; ++j) {
    const float sum = redS[j*4+0] + redS[j*4+1] + redS[j*4+2] + redS[j*4+3];
    const float sq  = redQ[j*4+0] + redQ[j*4+1] + redQ[j*4+2] + redQ[j*4+3];
    const float mu  = sum * (1.0f / D_DIM);
    const float var = sq * (1.0f / D_DIM) - mu * mu;
    const float inv = rsqrtf(var + 1e-5f);
    short4 o;
    short* op = &o.x;
#pragma unroll
    for (int c = 0; c < 4; ++c) {
      float t = (a[j][c] - mu) * inv * w4[c] + b4[c];
      float ge = 0.5f * t * (1.f + erff(t * 0.70710678118654752f));  // exact gelu
      op[c] = f2bs(ge);
    }
    *(short4*)((short*)act + (size_t)(m0 + j) * D_DIM + d0) = o;
  }
}

// ---------------------------------------------------------------------------
// Kernel 3: out = x + Act @ W^T + b_out.  Reverted to the round-0 verified
// 128x128 / BK=128 structure (the smaller-tile experiment was inconclusive
// and convln dominates; clean attribution this round).
// XOR-swizzled LDS: 16B chunk c of row r at slot (c ^ (r&7)).
// 4 waves (2x2), wave = 64x64 via 4x4 MFMA 16x16x32.
// A-frag: lane holds Act[m = l16][koff + j],  koff = (lane>>4)*8
// B-frag: lane holds W  [n = l16][koff + j]   (W row = out col)
// C/D   : col = lane&15, row = (lane>>4)*4 + reg
// ---------------------------------------------------------------------------
__global__ __launch_bounds__(256, 2) void gemm_kernel(const __hip_bfloat16* __restrict__ Act,
                                                      const __hip_bfloat16* __restrict__ Wb,
                                                      const float* __restrict__ x,
                                                      const float* __restrict__ bout,
                                                      float* __restrict__ out) {
  __shared__ short Al[128 * 128];  // 32 KB
  __shared__ short Bl[128 * 128];  // 32 KB
  const int tid  = threadIdx.x;
  const int lane = tid & 63;
  const int wave = tid >> 6;
  const int mBase = blockIdx.x * 128;
  const int nBase = blockIdx.y * 128;
  const int wm = (wave & 1) * 64;
  const int wn = (wave >> 1) * 64;
  const int l16 = lane & 15;
  const int kq  = lane >> 4;          // 0..3 k-quad

  // staging: thread t -> row (tid>>4) (+16/round, 8 rounds); 16 chunks/row,
  // this thread's LDS slot is (tid&15) => it fetches global chunk slot^(row&7)
  const int srow = tid >> 4;                       // 0..15
  const int cg   = (tid & 15) ^ (srow & 7);        // global 16B chunk fetched
  const short* Ag = (const short*)Act + (mBase + srow) * D_DIM + cg * 8;
  const short* Bg = (const short*)Wb  + (nBase + srow) * D_DIM + cg * 8;
  short* Als = Al + tid * 8;   // round r adds 2048 shorts (16 rows)
  short* Bls = Bl + tid * 8;

  f32x4 acc[4][4];
#pragma unroll
  for (int mt = 0; mt < 4; ++mt)
#pragma unroll
    for (int nt = 0; nt < 4; ++nt) acc[mt][nt] = (f32x4){0.f, 0.f, 0.f, 0.f};

  for (int k0 = 0; k0 < D_DIM; k0 += 128) {
    __syncthreads();                       // readers of previous tile done
#pragma unroll
    for (int r = 0; r < 8; ++r) {
      GLOAD16(Ag + r * 16 * D_DIM + k0, Als + r * 2048);
      GLOAD16(Bg + r * 16 * D_DIM + k0, Bls + r * 2048);
    }
    __syncthreads();                       // staged data visible
#pragma unroll
    for (int kk = 0; kk < 128; kk += 32) {
      bf16x8 af[4], bfr[4];
      const int cgr = (kk >> 3) + kq;      // global chunk this fragment needs
#pragma unroll
      for (int mt = 0; mt < 4; ++mt) {
        const int r = wm + mt * 16 + l16;
        af[mt] = *(const bf16x8*)&Al[r * 128 + ((cgr ^ (r & 7)) << 3)];
      }
#pragma unroll
      for (int nt = 0; nt < 4; ++nt) {
        const int r = wn + nt * 16 + l16;
        bfr[nt] = *(const bf16x8*)&Bl[r * 128 + ((cgr ^ (r & 7)) << 3)];
      }
#pragma unroll
      for (int mt = 0; mt < 4; ++mt)
#pragma unroll
        for (int nt = 0; nt < 4; ++nt)
          acc[mt][nt] = __builtin_amdgcn_mfma_f32_16x16x32_bf16(af[mt], bfr[nt], acc[mt][nt], 0, 0, 0);
    }
  }

  const int r0 = kq * 4;
#pragma unroll
  for (int mt = 0; mt < 4; ++mt) {
    const int row = mBase + wm + mt * 16 + r0;
#pragma unroll
    for (int nt = 0; nt < 4; ++nt) {
      const int col = nBase + wn + nt * 16 + l16;
      const float bo = bout[col];
#pragma unroll
      for (int r = 0; r < 4; ++r) {
        const int idx = (row + r) * D_DIM + col;
        out[idx] = x[idx] + acc[mt][nt][r] + bo;
      }
    }
  }
}

// ---------------------------------------------------------------------------
extern "C" void kernel_launch(void* const* d_in, const int* in_sizes, int n_in,
                              void* d_out, int out_size, void* d_ws, size_t ws_size,
                              hipStream_t stream) {
  const float* x    = (const float*)d_in[0];
  const float* A    = (const float*)d_in[1];
  const float* Bm   = (const float*)d_in[2];
  const float* Cm   = (const float*)d_in[3];
  const float* Dm   = (const float*)d_in[4];
  const float* lnw  = (const float*)d_in[5];
  const float* lnb  = (const float*)d_in[6];
  const float* Wout = (const float*)d_in[7];
  const float* bout = (const float*)d_in[8];
  float* out = (float*)d_out;

  char* ws = (char*)d_ws;
  float* gT            = (float*)ws;                        // 16*1024*4   = 64 KB
  __hip_bfloat16* Wb   = (__hip_bfloat16*)(ws + 262144);    // 1024*1024*2 = 2 MB, row-major
  __hip_bfloat16* Act  = (__hip_bfloat16*)(ws + 2359296);   // 8192*1024*2 = 16.75 MB, row-major

  taps_kernel<<<64, 256, 0, stream>>>(A, Bm, Cm, Dm, gT);
  convln_kernel<<<1536, 256, 0, stream>>>(x, gT, lnw, lnb, Wout, Wb, Act);
  gemm_kernel<<<dim3(64, 8), 256, 0, stream>>>(Act, Wb, x, bout, out);
}

// Round 4
// 145.693 us; speedup vs baseline: 1.0577x; 1.0198x over previous
//
#include <hip/hip_runtime.h>
#include <hip/hip_bf16.h>

#define D_DIM 1024
#define S_DIM 2048
#define B_DIM 4
#define KTAPS 16

typedef short bf16x8 __attribute__((ext_vector_type(8)));
typedef float f32x4 __attribute__((ext_vector_type(4)));
typedef short s16x8 __attribute__((ext_vector_type(8)));

// async global->LDS, 16B per lane (global_load_lds_dwordx4)
#define GLOAD16(gptr, lptr) \
  __builtin_amdgcn_global_load_lds((const __attribute__((address_space(1))) unsigned int*)(gptr), \
                                   (__attribute__((address_space(3))) unsigned int*)(lptr), 16, 0, 0)

static __device__ __forceinline__ short f2bs(float f) {
  __hip_bfloat16 h = __float2bfloat16(f);
  return *reinterpret_cast<short*>(&h);
}

// ---------------------------------------------------------------------------
// Kernel 1: taps. 64 blocks; impulse response g_k[d] = C_d.A_d^k.B_d
// (Dm folded into tap 0).
// ---------------------------------------------------------------------------
__global__ void taps_kernel(const float* __restrict__ A, const float* __restrict__ Bm,
                            const float* __restrict__ Cm, const float* __restrict__ Dm,
                            float* __restrict__ gT) {
  const int gb   = blockIdx.x;         // 0..63
  const int wid  = threadIdx.x >> 6;   // 0..3
  const int lane = threadIdx.x & 63;
  const int sub  = lane >> 4;          // 0..3 (channel within wave)
  const int n    = lane & 15;          // state index
  const int d    = gb * 16 + wid * 4 + sub;
  float Ar[16];
#pragma unroll
  for (int m = 0; m < 16; ++m) Ar[m] = A[d * 256 + n * 16 + m];
  float v = Bm[d * 16 + n];
  const float c   = Cm[d * 16 + n];
  const float dmv = Dm[d];
  const int base  = sub << 4;
  for (int k = 0; k < KTAPS; ++k) {
    float dot = c * v;
    dot += __shfl_xor(dot, 1);
    dot += __shfl_xor(dot, 2);
    dot += __shfl_xor(dot, 4);
    dot += __shfl_xor(dot, 8);
    if (k == 0) dot += dmv;            // fold the D x_t skip term into tap 0
    if (n == 0) gT[k * D_DIM + d] = dot;
    float nv = 0.f;
#pragma unroll
    for (int m = 0; m < 16; ++m) nv = fmaf(Ar[m], __shfl(v, base + m), nv);
    v = nv;
  }
}

// ---------------------------------------------------------------------------
// Kernel 2 (fused): conv(16 taps) + LayerNorm + exact GELU -> Act (bf16).
// 16 rows/block (was 8): halo amplification 31/16 = 1.94x (was 23/8 = 2.9x)
// -> x request traffic 96 -> 65 MB. All 31 window loads independent and
// issued up front (max MLP). Static register indexing only: rows s0-15..s0+7
// live in w[0..22], rows s0+8..s0+15 in w2[0..7]; every access index is
// compile-time (j,k unrolled). Peak live ~ 31*4 + 16*4 + misc ~= 220 VGPR
// under __launch_bounds__(256,2) (cap 256, 2 blocks/CU).
// Blocks [512,1024): vectorized W_out -> bf16 cast (8 elems/thread).
// ---------------------------------------------------------------------------
__global__ __launch_bounds__(256, 2) void convln_kernel(const float* __restrict__ x,
                                                        const float* __restrict__ gT,
                                                        const float* __restrict__ lnw,
                                                        const float* __restrict__ lnb,
                                                        const float* __restrict__ W,
                                                        __hip_bfloat16* __restrict__ Wb,
                                                        __hip_bfloat16* __restrict__ act) {
  if (blockIdx.x >= 512) {
    // ---- W cast: 512 blocks * 256 threads * 8 elems = 1024*1024 ----
    const int base = ((blockIdx.x - 512) * 256 + threadIdx.x) * 8;
    const f32x4 w0 = *(const f32x4*)(W + base);
    const f32x4 w1 = *(const f32x4*)(W + base + 4);
    s16x8 o;
#pragma unroll
    for (int c = 0; c < 4; ++c) { o[c] = f2bs(w0[c]); o[4 + c] = f2bs(w1[c]); }
    *(s16x8*)((short*)Wb + base) = o;
    return;
  }

  __shared__ float redS[64];   // [j*4 + wid], j=0..15
  __shared__ float redQ[64];
  const int m0  = blockIdx.x * 16;     // global row (0..8191); 2048%16==0 so
  const int b   = m0 >> 11;            // blocks never straddle a batch
  const int s0  = m0 & 2047;           // seq pos of row j=0
  const int tid = threadIdx.x;
  const int lane = tid & 63, wid = tid >> 6;
  const int d0  = tid * 4;
  const float* xb = x + ((size_t)b * S_DIM) * D_DIM + d0;

  // window: rows s0-15 .. s0+7 in w[0..22]; rows s0+8 .. s0+15 in w2[0..7].
  // All 31 loads independent, issued before any compute (full MLP).
  f32x4 w[23], w2[8];
#pragma unroll
  for (int i = 0; i < 23; ++i) {
    const int s = s0 - 15 + i;
    w[i] = (s >= 0) ? *(const f32x4*)(xb + (size_t)s * D_DIM) : (f32x4){0.f, 0.f, 0.f, 0.f};
  }
#pragma unroll
  for (int i = 0; i < 8; ++i)
    w2[i] = *(const f32x4*)(xb + (size_t)(s0 + 8 + i) * D_DIM);

  // conv: 16 rows, k-outer (g float4 streamed once per tap).
  // row offset t = j-k: t <= 7 -> w[t+15], t >= 8 -> w2[t-8] (all static).
  f32x4 a[16];
#pragma unroll
  for (int j = 0; j < 16; ++j) a[j] = (f32x4){0.f, 0.f, 0.f, 0.f};
#pragma unroll
  for (int k = 0; k < KTAPS; ++k) {
    const f32x4 g4 = *(const f32x4*)(gT + k * D_DIM + d0);
#pragma unroll
    for (int j = 0; j < 16; ++j) {
      const int t = j - k;
      const f32x4 xv = (t <= 7) ? w[t + 15] : w2[t - 8];
#pragma unroll
      for (int c = 0; c < 4; ++c) a[j][c] = fmaf(g4[c], xv[c], a[j][c]);
    }
  }

  // LN partial sums for all 16 rows -> one barrier
#pragma unroll
  for (int j = 0; j < 16; ++j) {
    float s = a[j][0] + a[j][1] + a[j][2] + a[j][3];
    float q = a[j][0]*a[j][0] + a[j][1]*a[j][1] + a[j][2]*a[j][2] + a[j][3]*a[j][3];
    s += __shfl_xor(s, 1);  s += __shfl_xor(s, 2);  s += __shfl_xor(s, 4);
    s += __shfl_xor(s, 8);  s += __shfl_xor(s, 16); s += __shfl_xor(s, 32);
    q += __shfl_xor(q, 1);  q += __shfl_xor(q, 2);  q += __shfl_xor(q, 4);
    q += __shfl_xor(q, 8);  q += __shfl_xor(q, 16); q += __shfl_xor(q, 32);
    if (lane == 0) { redS[j * 4 + wid] = s; redQ[j * 4 + wid] = q; }
  }
  __syncthreads();

  const f32x4 w4 = *(const f32x4*)&lnw[d0];
  const f32x4 b4 = *(const f32x4*)&lnb[d0];
#pragma unroll
  for (int j = 0; j < 16; ++j) {
    const float sum = redS[j*4+0] + redS[j*4+1] + redS[j*4+2] + redS[j*4+3];
    const float sq  = redQ[j*4+0] + redQ[j*4+1] + redQ[j*4+2] + redQ[j*4+3];
    const float mu  = sum * (1.0f / D_DIM);
    const float var = sq * (1.0f / D_DIM) - mu * mu;
    const float inv = rsqrtf(var + 1e-5f);
    short4 o;
    short* op = &o.x;
#pragma unroll
    for (int c = 0; c < 4; ++c) {
      float t = (a[j][c] - mu) * inv * w4[c] + b4[c];
      float ge = 0.5f * t * (1.f + erff(t * 0.70710678118654752f));  // exact gelu
      op[c] = f2bs(ge);
    }
    *(short4*)((short*)act + (size_t)(m0 + j) * D_DIM + d0) = o;
  }
}

// ---------------------------------------------------------------------------
// Kernel 3: out = x + Act @ W^T + b_out.  Round-0 verified 128x128 / BK=128
// structure (unchanged this round for attribution).
// XOR-swizzled LDS: 16B chunk c of row r at slot (c ^ (r&7)).
// 4 waves (2x2), wave = 64x64 via 4x4 MFMA 16x16x32.
// A-frag: lane holds Act[m = l16][koff + j],  koff = (lane>>4)*8
// B-frag: lane holds W  [n = l16][koff + j]   (W row = out col)
// C/D   : col = lane&15, row = (lane>>4)*4 + reg
// ---------------------------------------------------------------------------
__global__ __launch_bounds__(256, 2) void gemm_kernel(const __hip_bfloat16* __restrict__ Act,
                                                      const __hip_bfloat16* __restrict__ Wb,
                                                      const float* __restrict__ x,
                                                      const float* __restrict__ bout,
                                                      float* __restrict__ out) {
  __shared__ short Al[128 * 128];  // 32 KB
  __shared__ short Bl[128 * 128];  // 32 KB
  const int tid  = threadIdx.x;
  const int lane = tid & 63;
  const int wave = tid >> 6;
  const int mBase = blockIdx.x * 128;
  const int nBase = blockIdx.y * 128;
  const int wm = (wave & 1) * 64;
  const int wn = (wave >> 1) * 64;
  const int l16 = lane & 15;
  const int kq  = lane >> 4;          // 0..3 k-quad

  // staging: thread t -> row (tid>>4) (+16/round, 8 rounds); 16 chunks/row,
  // this thread's LDS slot is (tid&15) => it fetches global chunk slot^(row&7)
  const int srow = tid >> 4;                       // 0..15
  const int cg   = (tid & 15) ^ (srow & 7);        // global 16B chunk fetched
  const short* Ag = (const short*)Act + (mBase + srow) * D_DIM + cg * 8;
  const short* Bg = (const short*)Wb  + (nBase + srow) * D_DIM + cg * 8;
  short* Als = Al + tid * 8;   // round r adds 2048 shorts (16 rows)
  short* Bls = Bl + tid * 8;

  f32x4 acc[4][4];
#pragma unroll
  for (int mt = 0; mt < 4; ++mt)
#pragma unroll
    for (int nt = 0; nt < 4; ++nt) acc[mt][nt] = (f32x4){0.f, 0.f, 0.f, 0.f};

  for (int k0 = 0; k0 < D_DIM; k0 += 128) {
    __syncthreads();                       // readers of previous tile done
#pragma unroll
    for (int r = 0; r < 8; ++r) {
      GLOAD16(Ag + r * 16 * D_DIM + k0, Als + r * 2048);
      GLOAD16(Bg + r * 16 * D_DIM + k0, Bls + r * 2048);
    }
    __syncthreads();                       // staged data visible
#pragma unroll
    for (int kk = 0; kk < 128; kk += 32) {
      bf16x8 af[4], bfr[4];
      const int cgr = (kk >> 3) + kq;      // global chunk this fragment needs
#pragma unroll
      for (int mt = 0; mt < 4; ++mt) {
        const int r = wm + mt * 16 + l16;
        af[mt] = *(const bf16x8*)&Al[r * 128 + ((cgr ^ (r & 7)) << 3)];
      }
#pragma unroll
      for (int nt = 0; nt < 4; ++nt) {
        const int r = wn + nt * 16 + l16;
        bfr[nt] = *(const bf16x8*)&Bl[r * 128 + ((cgr ^ (r & 7)) << 3)];
      }
#pragma unroll
      for (int mt = 0; mt < 4; ++mt)
#pragma unroll
        for (int nt = 0; nt < 4; ++nt)
          acc[mt][nt] = __builtin_amdgcn_mfma_f32_16x16x32_bf16(af[mt], bfr[nt], acc[mt][nt], 0, 0, 0);
    }
  }

  const int r0 = kq * 4;
#pragma unroll
  for (int mt = 0; mt < 4; ++mt) {
    const int row = mBase + wm + mt * 16 + r0;
#pragma unroll
    for (int nt = 0; nt < 4; ++nt) {
      const int col = nBase + wn + nt * 16 + l16;
      const float bo = bout[col];
#pragma unroll
      for (int r = 0; r < 4; ++r) {
        const int idx = (row + r) * D_DIM + col;
        out[idx] = x[idx] + acc[mt][nt][r] + bo;
      }
    }
  }
}

// ---------------------------------------------------------------------------
extern "C" void kernel_launch(void* const* d_in, const int* in_sizes, int n_in,
                              void* d_out, int out_size, void* d_ws, size_t ws_size,
                              hipStream_t stream) {
  const float* x    = (const float*)d_in[0];
  const float* A    = (const float*)d_in[1];
  const float* Bm   = (const float*)d_in[2];
  const float* Cm   = (const float*)d_in[3];
  const float* Dm   = (const float*)d_in[4];
  const float* lnw  = (const float*)d_in[5];
  const float* lnb  = (const float*)d_in[6];
  const float* Wout = (const float*)d_in[7];
  const float* bout = (const float*)d_in[8];
  float* out = (float*)d_out;

  char* ws = (char*)d_ws;
  float* gT            = (float*)ws;                        // 16*1024*4   = 64 KB
  __hip_bfloat16* Wb   = (__hip_bfloat16*)(ws + 262144);    // 1024*1024*2 = 2 MB, row-major
  __hip_bfloat16* Act  = (__hip_bfloat16*)(ws + 2359296);   // 8192*1024*2 = 16.75 MB, row-major

  taps_kernel<<<64, 256, 0, stream>>>(A, Bm, Cm, Dm, gT);
  convln_kernel<<<1024, 256, 0, stream>>>(x, gT, lnw, lnb, Wout, Wb, Act);
  gemm_kernel<<<dim3(64, 8), 256, 0, stream>>>(Act, Wb, x, bout, out);
}